// Round 7
// baseline (1280.363 us; speedup 1.0000x reference)
//
#include <hip/hip_runtime.h>

// Problem constants (fixed by the reference): T=512, B=64, I=256, H=512.
#define T_DIM 512
#define B_DIM 64
#define I_DIM 256
#define H_DIM 512
#define BH_DIM (B_DIM * H_DIM)   // 32768

// ---------------------------------------------------------------------------
// Round-7: fused, dual-batch, phase-staggered scan.
// Grid 256 = 8 row-chunks (rb, 64 rows) x 32 batch-pairs (bg -> batches bg,
// bg+32). 512 threads. Co-residency: 256 blocks x 8 waves = 2048 waves =
// chip capacity; LDS 78 KB, VGPRs ~<160 -> >=1 block/CU guaranteed.
//
// Why dual-batch: R6 showed the step is co-limited by the CU-shared LDS pipe
// (W_ih stream = 4 B/MAC) and the publish->detect L3 latency. Two batches
// (a) amortize every W_ih LDS read across both batches (2 B/MAC), and
// (b) phase-stagger the two exchanges so each poll's latency is covered by
// the other batch's compute phase.
//
// Thread map: rg = tid>>5 (0..15) -> rows j0 = rb*64 + rg*4 .. +3;
// cg = tid&31 -> float4-col {i*32+cg}. hh: i=0..3; ih: i=0..1.
// W_hh in regs w[4][4] (64 VGPRs). W_ih chunk in LDS (64 KB).
// Reduction: 5-deep shfl_xor butterfly over the 32 cg lanes (masks<=16 stay
// in the wave half). Publish: lanes cg<4 -> tagged 8B relaxed agent-scope
// words (R5 protocol; parity double-buffer, ABA-safe, fence-free).
// ---------------------------------------------------------------------------
__global__ __launch_bounds__(512, 2) void rnn_fused2(
    const float* __restrict__ x, const float* __restrict__ wih,
    const float* __restrict__ whh, const float* __restrict__ bih,
    const float* __restrict__ bhh, float* __restrict__ out,
    unsigned long long* __restrict__ stage) {
  __shared__ __align__(16) float4 wihs4[64 * 64];   // 64 KB: my W_ih rows
  __shared__ __align__(16) float hbuf[2][2][H_DIM]; // [AB][parity][j] 8 KB
  __shared__ __align__(16) float4 xbuf4[2][3][64];  // [AB][slot][quad] 6 KB

  const int bg  = blockIdx.x & 31;
  const int rb  = blockIdx.x >> 5;       // row-chunk 0..7
  const int bA  = bg;
  const int bB  = bg + 32;
  const int tid = threadIdx.x;           // 0..511
  const int rg  = tid >> 5;              // 0..15
  const int cg  = tid & 31;              // 0..31
  const int j0  = rb * 64 + rg * 4;      // first of my 4 rows

  // poll target: one foreign row each for threads 0..447 (skip own 64 rows)
  const int pj = (tid < rb * 64) ? tid : tid + 64;

  // ---- W_hh chunk -> registers (once): 4 rows x 4 float4 = 64 VGPRs ----
  float4 w[4][4];
#pragma unroll
  for (int r = 0; r < 4; r++) {
    const float4* wr = (const float4*)(whh + (size_t)(j0 + r) * H_DIM);
#pragma unroll
    for (int i = 0; i < 4; i++) w[r][i] = wr[i * 32 + cg];
  }

  // ---- W_ih chunk -> LDS (once; coalesced) ----
  {
    const float4* wg = (const float4*)(wih + (size_t)rb * 64 * I_DIM);
#pragma unroll
    for (int q = 0; q < 8; q++) wihs4[q * 512 + tid] = wg[q * 512 + tid];
  }

  // ---- x_0, x_1 preload for both batches ----
  const float4* xg = (const float4*)x;  // idx = (t*B_DIM + b)*64 + c4
  if (tid < 128) {
    const int ab = tid >> 6;            // 0 = A, 1 = B
    const int c  = tid & 63;
    const int bb = ab ? bB : bA;
    xbuf4[ab][0][c] = xg[((size_t)0 * B_DIM + bb) * 64 + c];
    xbuf4[ab][1][c] = xg[((size_t)1 * B_DIM + bb) * 64 + c];
  }

  float bias = 0.f;
  if (cg < 4) bias = bih[j0 + cg] + bhh[j0 + cg];

  float* __restrict__ outA = out + (size_t)bA * H_DIM;  // t-stride = BH_DIM
  float* __restrict__ outB = out + (size_t)bB * H_DIM;
  unsigned long long* __restrict__ stgA0 = stage + (size_t)bA * H_DIM;
  unsigned long long* __restrict__ stgA1 = stage + (size_t)(64 + bA) * H_DIM;
  unsigned long long* __restrict__ stgB0 = stage + (size_t)bB * H_DIM;
  unsigned long long* __restrict__ stgB1 = stage + (size_t)(64 + bB) * H_DIM;

  __syncthreads();  // W_ih, x0, x1 staged

  float hlastA = 0.f, hlastB = 0.f;

  // ---- t = 0: h_0 = relu(W_ih x_0 + bias) for both batches ----
  {
    float aA0 = 0.f, aA1 = 0.f, aA2 = 0.f, aA3 = 0.f;
    float aB0 = 0.f, aB1 = 0.f, aB2 = 0.f, aB3 = 0.f;
    const float4* wr = &wihs4[(rg * 4) * 64];
    const float4* xa = &xbuf4[0][0][0];
    const float4* xb = &xbuf4[1][0][0];
#pragma unroll
    for (int i = 0; i < 2; i++) {
      const int q = i * 32 + cg;
      const float4 xva = xa[q];
      const float4 xvb = xb[q];
      const float4 q0 = wr[0 * 64 + q];
      const float4 q1 = wr[1 * 64 + q];
      const float4 q2 = wr[2 * 64 + q];
      const float4 q3 = wr[3 * 64 + q];
      aA0 = fmaf(q0.x, xva.x, aA0); aA0 = fmaf(q0.y, xva.y, aA0);
      aA0 = fmaf(q0.z, xva.z, aA0); aA0 = fmaf(q0.w, xva.w, aA0);
      aA1 = fmaf(q1.x, xva.x, aA1); aA1 = fmaf(q1.y, xva.y, aA1);
      aA1 = fmaf(q1.z, xva.z, aA1); aA1 = fmaf(q1.w, xva.w, aA1);
      aA2 = fmaf(q2.x, xva.x, aA2); aA2 = fmaf(q2.y, xva.y, aA2);
      aA2 = fmaf(q2.z, xva.z, aA2); aA2 = fmaf(q2.w, xva.w, aA2);
      aA3 = fmaf(q3.x, xva.x, aA3); aA3 = fmaf(q3.y, xva.y, aA3);
      aA3 = fmaf(q3.z, xva.z, aA3); aA3 = fmaf(q3.w, xva.w, aA3);
      aB0 = fmaf(q0.x, xvb.x, aB0); aB0 = fmaf(q0.y, xvb.y, aB0);
      aB0 = fmaf(q0.z, xvb.z, aB0); aB0 = fmaf(q0.w, xvb.w, aB0);
      aB1 = fmaf(q1.x, xvb.x, aB1); aB1 = fmaf(q1.y, xvb.y, aB1);
      aB1 = fmaf(q1.z, xvb.z, aB1); aB1 = fmaf(q1.w, xvb.w, aB1);
      aB2 = fmaf(q2.x, xvb.x, aB2); aB2 = fmaf(q2.y, xvb.y, aB2);
      aB2 = fmaf(q2.z, xvb.z, aB2); aB2 = fmaf(q2.w, xvb.w, aB2);
      aB3 = fmaf(q3.x, xvb.x, aB3); aB3 = fmaf(q3.y, xvb.y, aB3);
      aB3 = fmaf(q3.z, xvb.z, aB3); aB3 = fmaf(q3.w, xvb.w, aB3);
    }
#pragma unroll
    for (int m = 1; m <= 16; m <<= 1) {
      aA0 += __shfl_xor(aA0, m, 64); aA1 += __shfl_xor(aA1, m, 64);
      aA2 += __shfl_xor(aA2, m, 64); aA3 += __shfl_xor(aA3, m, 64);
      aB0 += __shfl_xor(aB0, m, 64); aB1 += __shfl_xor(aB1, m, 64);
      aB2 += __shfl_xor(aB2, m, 64); aB3 += __shfl_xor(aB3, m, 64);
    }
    if (cg < 4) {
      const int j = j0 + cg;
      union { float f; unsigned int u; } cv;
      const float accA = (cg == 0) ? aA0 : (cg == 1) ? aA1 : (cg == 2) ? aA2 : aA3;
      const float hA = fmaxf(accA + bias, 0.f);
      cv.f = hA;
      __hip_atomic_store(&stgA0[j], (unsigned long long)cv.u,
                         __ATOMIC_RELAXED, __HIP_MEMORY_SCOPE_AGENT);
      outA[j] = hA; hbuf[0][0][j] = hA; hlastA = hA;
      const float accB = (cg == 0) ? aB0 : (cg == 1) ? aB1 : (cg == 2) ? aB2 : aB3;
      const float hB = fmaxf(accB + bias, 0.f);
      cv.f = hB;
      __hip_atomic_store(&stgB0[j], (unsigned long long)cv.u,
                         __ATOMIC_RELAXED, __HIP_MEMORY_SCOPE_AGENT);
      outB[j] = hB; hbuf[1][0][j] = hB; hlastB = hB;
    }
    // prefetch x_2 -> slot 2 (no prior readers)
    if (tid < 128) {
      const int ab = tid >> 6;
      const int c  = tid & 63;
      const int bb = ab ? bB : bA;
      xbuf4[ab][2][c] = xg[((size_t)2 * B_DIM + bb) * 64 + c];
    }
  }

  // ---- main scan ----
  for (int t = 1; t < T_DIM; t++) {
    const int p = (t - 1) & 1;  // parity of h_{t-1}
    const int s = t % 3;        // x slot
    float* o_tA = outA + (size_t)t * BH_DIM;
    float* o_tB = outB + (size_t)t * BH_DIM;

    // === shared ih-pass on x_t for BOTH batches (pre-poll latency filler;
    //     each W_ih read feeds 8 MACs) ===
    float aA0 = 0.f, aA1 = 0.f, aA2 = 0.f, aA3 = 0.f;
    float aB0 = 0.f, aB1 = 0.f, aB2 = 0.f, aB3 = 0.f;
    {
      const float4* wr = &wihs4[(rg * 4) * 64];
      const float4* xa = &xbuf4[0][s][0];
      const float4* xb = &xbuf4[1][s][0];
#pragma unroll
      for (int i = 0; i < 2; i++) {
        const int q = i * 32 + cg;
        const float4 xva = xa[q];
        const float4 xvb = xb[q];
        const float4 q0 = wr[0 * 64 + q];
        const float4 q1 = wr[1 * 64 + q];
        const float4 q2 = wr[2 * 64 + q];
        const float4 q3 = wr[3 * 64 + q];
        aA0 = fmaf(q0.x, xva.x, aA0); aA0 = fmaf(q0.y, xva.y, aA0);
        aA0 = fmaf(q0.z, xva.z, aA0); aA0 = fmaf(q0.w, xva.w, aA0);
        aA1 = fmaf(q1.x, xva.x, aA1); aA1 = fmaf(q1.y, xva.y, aA1);
        aA1 = fmaf(q1.z, xva.z, aA1); aA1 = fmaf(q1.w, xva.w, aA1);
        aA2 = fmaf(q2.x, xva.x, aA2); aA2 = fmaf(q2.y, xva.y, aA2);
        aA2 = fmaf(q2.z, xva.z, aA2); aA2 = fmaf(q2.w, xva.w, aA2);
        aA3 = fmaf(q3.x, xva.x, aA3); aA3 = fmaf(q3.y, xva.y, aA3);
        aA3 = fmaf(q3.z, xva.z, aA3); aA3 = fmaf(q3.w, xva.w, aA3);
        aB0 = fmaf(q0.x, xvb.x, aB0); aB0 = fmaf(q0.y, xvb.y, aB0);
        aB0 = fmaf(q0.z, xvb.z, aB0); aB0 = fmaf(q0.w, xvb.w, aB0);
        aB1 = fmaf(q1.x, xvb.x, aB1); aB1 = fmaf(q1.y, xvb.y, aB1);
        aB1 = fmaf(q1.z, xvb.z, aB1); aB1 = fmaf(q1.w, xvb.w, aB1);
        aB2 = fmaf(q2.x, xvb.x, aB2); aB2 = fmaf(q2.y, xvb.y, aB2);
        aB2 = fmaf(q2.z, xvb.z, aB2); aB2 = fmaf(q2.w, xvb.w, aB2);
        aB3 = fmaf(q3.x, xvb.x, aB3); aB3 = fmaf(q3.y, xvb.y, aB3);
        aB3 = fmaf(q3.z, xvb.z, aB3); aB3 = fmaf(q3.w, xvb.w, aB3);
      }
    }

    // issue x_{t+2} global load early (latency off-path)
    float4 xpf = make_float4(0.f, 0.f, 0.f, 0.f);
    const bool do_pf = (tid < 128) && (t + 2 < T_DIM);
    if (do_pf) {
      const int bb = (tid < 64) ? bA : bB;
      xpf = xg[((size_t)(t + 2) * B_DIM + bb) * 64 + (tid & 63)];
    }

    // === phase A: poll + hh + publish for batch A ===
    if (tid < 448) {
      unsigned long long* slot = (p ? stgA1 : stgA0) + pj;
      const unsigned int want = (unsigned int)(t - 1);
      unsigned long long v;
      do {
        v = __hip_atomic_load(slot, __ATOMIC_RELAXED, __HIP_MEMORY_SCOPE_AGENT);
      } while ((unsigned int)(v >> 32) != want);
      union { unsigned int u; float f; } cv; cv.u = (unsigned int)v;
      hbuf[0][p][pj] = cv.f;
    }
    __syncthreads();

    // commit x_{t+2} (readers >= 2 barriers away)
    if (do_pf) xbuf4[tid >> 6][(t + 2) % 3][tid & 63] = xpf;

    {
      const float* hbp = hbuf[0][p];
#pragma unroll
      for (int i = 0; i < 4; i++) {
        const float4 hv = ((const float4*)hbp)[i * 32 + cg];
        aA0 = fmaf(w[0][i].x, hv.x, aA0); aA0 = fmaf(w[0][i].y, hv.y, aA0);
        aA0 = fmaf(w[0][i].z, hv.z, aA0); aA0 = fmaf(w[0][i].w, hv.w, aA0);
        aA1 = fmaf(w[1][i].x, hv.x, aA1); aA1 = fmaf(w[1][i].y, hv.y, aA1);
        aA1 = fmaf(w[1][i].z, hv.z, aA1); aA1 = fmaf(w[1][i].w, hv.w, aA1);
        aA2 = fmaf(w[2][i].x, hv.x, aA2); aA2 = fmaf(w[2][i].y, hv.y, aA2);
        aA2 = fmaf(w[2][i].z, hv.z, aA2); aA2 = fmaf(w[2][i].w, hv.w, aA2);
        aA3 = fmaf(w[3][i].x, hv.x, aA3); aA3 = fmaf(w[3][i].y, hv.y, aA3);
        aA3 = fmaf(w[3][i].z, hv.z, aA3); aA3 = fmaf(w[3][i].w, hv.w, aA3);
      }
    }
#pragma unroll
    for (int m = 1; m <= 16; m <<= 1) {
      aA0 += __shfl_xor(aA0, m, 64); aA1 += __shfl_xor(aA1, m, 64);
      aA2 += __shfl_xor(aA2, m, 64); aA3 += __shfl_xor(aA3, m, 64);
    }
    if (cg < 4) {
      const float acc = (cg == 0) ? aA0 : (cg == 1) ? aA1 : (cg == 2) ? aA2 : aA3;
      const float h = fmaxf(acc + bias, 0.f);
      const int j = j0 + cg;
      union { float f; unsigned int u; } cv; cv.f = h;
      const unsigned long long tag = (unsigned long long)(unsigned int)t << 32;
      __hip_atomic_store(&((t & 1) ? stgA1 : stgA0)[j], tag | cv.u,
                         __ATOMIC_RELAXED, __HIP_MEMORY_SCOPE_AGENT);
      o_tA[j] = h; hbuf[0][t & 1][j] = h; hlastA = h;
    }

    // === phase B: poll + hh + publish for batch B (A's publish->detect
    //     latency for other blocks is covered by this phase, and B's poll
    //     latency was covered by phase A) ===
    if (tid < 448) {
      unsigned long long* slot = (p ? stgB1 : stgB0) + pj;
      const unsigned int want = (unsigned int)(t - 1);
      unsigned long long v;
      do {
        v = __hip_atomic_load(slot, __ATOMIC_RELAXED, __HIP_MEMORY_SCOPE_AGENT);
      } while ((unsigned int)(v >> 32) != want);
      union { unsigned int u; float f; } cv; cv.u = (unsigned int)v;
      hbuf[1][p][pj] = cv.f;
    }
    __syncthreads();

    {
      const float* hbp = hbuf[1][p];
#pragma unroll
      for (int i = 0; i < 4; i++) {
        const float4 hv = ((const float4*)hbp)[i * 32 + cg];
        aB0 = fmaf(w[0][i].x, hv.x, aB0); aB0 = fmaf(w[0][i].y, hv.y, aB0);
        aB0 = fmaf(w[0][i].z, hv.z, aB0); aB0 = fmaf(w[0][i].w, hv.w, aB0);
        aB1 = fmaf(w[1][i].x, hv.x, aB1); aB1 = fmaf(w[1][i].y, hv.y, aB1);
        aB1 = fmaf(w[1][i].z, hv.z, aB1); aB1 = fmaf(w[1][i].w, hv.w, aB1);
        aB2 = fmaf(w[2][i].x, hv.x, aB2); aB2 = fmaf(w[2][i].y, hv.y, aB2);
        aB2 = fmaf(w[2][i].z, hv.z, aB2); aB2 = fmaf(w[2][i].w, hv.w, aB2);
        aB3 = fmaf(w[3][i].x, hv.x, aB3); aB3 = fmaf(w[3][i].y, hv.y, aB3);
        aB3 = fmaf(w[3][i].z, hv.z, aB3); aB3 = fmaf(w[3][i].w, hv.w, aB3);
      }
    }
#pragma unroll
    for (int m = 1; m <= 16; m <<= 1) {
      aB0 += __shfl_xor(aB0, m, 64); aB1 += __shfl_xor(aB1, m, 64);
      aB2 += __shfl_xor(aB2, m, 64); aB3 += __shfl_xor(aB3, m, 64);
    }
    if (cg < 4) {
      const float acc = (cg == 0) ? aB0 : (cg == 1) ? aB1 : (cg == 2) ? aB2 : aB3;
      const float h = fmaxf(acc + bias, 0.f);
      const int j = j0 + cg;
      union { float f; unsigned int u; } cv; cv.f = h;
      const unsigned long long tag = (unsigned long long)(unsigned int)t << 32;
      __hip_atomic_store(&((t & 1) ? stgB1 : stgB0)[j], tag | cv.u,
                         __ATOMIC_RELAXED, __HIP_MEMORY_SCOPE_AGENT);
      o_tB[j] = h; hbuf[1][t & 1][j] = h; hlastB = h;
    }
  }

  // h_final = h_{T-1} for both batches
  if (cg < 4) {
    const int j = j0 + cg;
    out[(size_t)T_DIM * BH_DIM + (size_t)bA * H_DIM + j] = hlastA;
    out[(size_t)T_DIM * BH_DIM + (size_t)bB * H_DIM + j] = hlastB;
  }
}

extern "C" void kernel_launch(void* const* d_in, const int* in_sizes, int n_in,
                              void* d_out, int out_size, void* d_ws, size_t ws_size,
                              hipStream_t stream) {
  const float* x   = (const float*)d_in[0];  // [T,B,I]
  const float* wih = (const float*)d_in[1];  // [H,I]
  const float* whh = (const float*)d_in[2];  // [H,H]
  const float* bih = (const float*)d_in[3];  // [H]
  const float* bhh = (const float*)d_in[4];  // [H]
  float* out = (float*)d_out;                // [T,B,H] output ++ [B,H] h_final
  // staging: 2 parities x 64 batches x 512 tagged 8B words = 512 KB
  unsigned long long* stage = (unsigned long long*)d_ws;

  rnn_fused2<<<256, 512, 0, stream>>>(x, wih, whh, bih, bhh, out, stage);
}